// Round 1
// baseline (49.889 us; speedup 1.0000x reference)
//
#include <hip/hip_runtime.h>
#include <math.h>

// Problem constants (match reference)
#define DDIM   1024
#define BATCH  2048        // B; image_features has 2*B rows
#define MROWS  16384
#define TEMP_INV 10.0f     // 1/0.1
#define EPSN   1e-8f

// Launch geometry
#define NA_BLOCKS 64
#define NA_THREADS 1024    // 16 waves/block -> 1024 waves total, 16 rows/wave
#define NC_BLOCKS 512
#define NC_THREADS 256     // 4 waves/block -> 2048 waves = B pairs

// ws layout in floats
#define OFF_PART 0                          // NA_BLOCKS * DDIM partial s
#define OFF_S    (NA_BLOCKS * DDIM)         // DDIM final s
#define OFF_LP   (OFF_S + DDIM)             // NC_BLOCKS loss partials

__device__ __forceinline__ float wave_sum(float v) {
    v += __shfl_xor(v, 32);
    v += __shfl_xor(v, 16);
    v += __shfl_xor(v, 8);
    v += __shfl_xor(v, 4);
    v += __shfl_xor(v, 2);
    v += __shfl_xor(v, 1);
    return v;
}

__device__ __forceinline__ float softplus_stable(float d) {
    // log(1 + exp(d)) computed stably
    return fmaxf(d, 0.0f) + log1pf(expf(-fabsf(d)));
}

// Kernel A: s_partial[block][d] = sum over assigned memory-bank rows of row/||row||
__global__ __launch_bounds__(NA_THREADS)
void mb_sum_kernel(const float* __restrict__ mb, float* __restrict__ ws) {
    __shared__ float sb[DDIM];
    const int tid = threadIdx.x;
    sb[tid] = 0.0f;                 // blockDim.x == DDIM
    __syncthreads();

    const int lane  = tid & 63;
    const int wave  = tid >> 6;
    const int gwave = blockIdx.x * (NA_THREADS / 64) + wave;
    const int nwaves = NA_BLOCKS * (NA_THREADS / 64);

    float4 a0 = {0,0,0,0}, a1 = {0,0,0,0}, a2 = {0,0,0,0}, a3 = {0,0,0,0};

    for (int row = gwave; row < MROWS; row += nwaves) {
        const float4* rp = reinterpret_cast<const float4*>(mb + (size_t)row * DDIM);
        float4 v0 = rp[lane];
        float4 v1 = rp[64 + lane];
        float4 v2 = rp[128 + lane];
        float4 v3 = rp[192 + lane];

        float ssq = v0.x*v0.x + v0.y*v0.y + v0.z*v0.z + v0.w*v0.w
                  + v1.x*v1.x + v1.y*v1.y + v1.z*v1.z + v1.w*v1.w
                  + v2.x*v2.x + v2.y*v2.y + v2.z*v2.z + v2.w*v2.w
                  + v3.x*v3.x + v3.y*v3.y + v3.z*v3.z + v3.w*v3.w;
        ssq = wave_sum(ssq);
        float inv = 1.0f / fmaxf(sqrtf(ssq), EPSN);

        a0.x += v0.x*inv; a0.y += v0.y*inv; a0.z += v0.z*inv; a0.w += v0.w*inv;
        a1.x += v1.x*inv; a1.y += v1.y*inv; a1.z += v1.z*inv; a1.w += v1.w*inv;
        a2.x += v2.x*inv; a2.y += v2.y*inv; a2.z += v2.z*inv; a2.w += v2.w*inv;
        a3.x += v3.x*inv; a3.y += v3.y*inv; a3.z += v3.z*inv; a3.w += v3.w*inv;
    }

    // Accumulate 16 waves into the block-local s via LDS atomics (element
    // index = c*256 + lane*4 + j; 16-way max contention, trivial cost).
    const int b = lane * 4;
    atomicAdd(&sb[b + 0],        a0.x); atomicAdd(&sb[b + 1],        a0.y);
    atomicAdd(&sb[b + 2],        a0.z); atomicAdd(&sb[b + 3],        a0.w);
    atomicAdd(&sb[256 + b + 0],  a1.x); atomicAdd(&sb[256 + b + 1],  a1.y);
    atomicAdd(&sb[256 + b + 2],  a1.z); atomicAdd(&sb[256 + b + 3],  a1.w);
    atomicAdd(&sb[512 + b + 0],  a2.x); atomicAdd(&sb[512 + b + 1],  a2.y);
    atomicAdd(&sb[512 + b + 2],  a2.z); atomicAdd(&sb[512 + b + 3],  a2.w);
    atomicAdd(&sb[768 + b + 0],  a3.x); atomicAdd(&sb[768 + b + 1],  a3.y);
    atomicAdd(&sb[768 + b + 2],  a3.z); atomicAdd(&sb[768 + b + 3],  a3.w);
    __syncthreads();

    ws[OFF_PART + (size_t)blockIdx.x * DDIM + tid] = sb[tid];
}

// Kernel B: s[d] = sum over blocks of s_partial[block][d]   (grid 4 x 256)
__global__ __launch_bounds__(256)
void s_reduce_kernel(float* __restrict__ ws) {
    const int d = blockIdx.x * 256 + threadIdx.x;
    float s = 0.0f;
    #pragma unroll 8
    for (int b = 0; b < NA_BLOCKS; ++b)
        s += ws[OFF_PART + (size_t)b * DDIM + d];
    ws[OFF_S + d] = s;
}

// Kernel C: one wave per pair (i, i+B): pos/neg -> softplus contributions
__global__ __launch_bounds__(NC_THREADS)
void img_kernel(const float* __restrict__ img, float* __restrict__ ws) {
    __shared__ float ls[NC_THREADS / 64];
    const int tid  = threadIdx.x;
    const int lane = tid & 63;
    const int wave = tid >> 6;
    const int pair = blockIdx.x * (NC_THREADS / 64) + wave;   // [0, BATCH)

    const float4* ap = reinterpret_cast<const float4*>(img + (size_t)pair * DDIM);
    const float4* bp = reinterpret_cast<const float4*>(img + (size_t)(pair + BATCH) * DDIM);
    const float4* sp = reinterpret_cast<const float4*>(ws + OFF_S);

    float ssqa = 0.f, ssqb = 0.f, dab = 0.f, das = 0.f, dbs = 0.f;

    #pragma unroll
    for (int c = 0; c < 4; ++c) {
        float4 va = ap[c * 64 + lane];
        float4 vb = bp[c * 64 + lane];
        float4 vs = sp[c * 64 + lane];
        ssqa = fmaf(va.x, va.x, ssqa); ssqa = fmaf(va.y, va.y, ssqa);
        ssqa = fmaf(va.z, va.z, ssqa); ssqa = fmaf(va.w, va.w, ssqa);
        ssqb = fmaf(vb.x, vb.x, ssqb); ssqb = fmaf(vb.y, vb.y, ssqb);
        ssqb = fmaf(vb.z, vb.z, ssqb); ssqb = fmaf(vb.w, vb.w, ssqb);
        dab  = fmaf(va.x, vb.x, dab);  dab  = fmaf(va.y, vb.y, dab);
        dab  = fmaf(va.z, vb.z, dab);  dab  = fmaf(va.w, vb.w, dab);
        das  = fmaf(va.x, vs.x, das);  das  = fmaf(va.y, vs.y, das);
        das  = fmaf(va.z, vs.z, das);  das  = fmaf(va.w, vs.w, das);
        dbs  = fmaf(vb.x, vs.x, dbs);  dbs  = fmaf(vb.y, vs.y, dbs);
        dbs  = fmaf(vb.z, vs.z, dbs);  dbs  = fmaf(vb.w, vs.w, dbs);
    }

    ssqa = wave_sum(ssqa);
    ssqb = wave_sum(ssqb);
    dab  = wave_sum(dab);
    das  = wave_sum(das);
    dbs  = wave_sum(dbs);

    if (lane == 0) {
        float ia  = 1.0f / fmaxf(sqrtf(ssqa), EPSN);
        float ib  = 1.0f / fmaxf(sqrtf(ssqb), EPSN);
        float pos = dab * ia * ib * TEMP_INV;      // shared by rows i and i+B
        float na  = das * ia * TEMP_INV;           // neg for row i
        float nb  = dbs * ib * TEMP_INV;           // neg for row i+B
        ls[wave] = softplus_stable(na - pos) + softplus_stable(nb - pos);
    }
    __syncthreads();
    if (tid == 0)
        ws[OFF_LP + blockIdx.x] = ls[0] + ls[1] + ls[2] + ls[3];
}

// Kernel D: final scalar = mean over 2B rows
__global__ __launch_bounds__(256)
void final_kernel(const float* __restrict__ ws, float* __restrict__ out) {
    __shared__ float ls[4];
    const int tid  = threadIdx.x;
    const int lane = tid & 63;
    const int wave = tid >> 6;
    float v = ws[OFF_LP + tid] + ws[OFF_LP + 256 + tid];
    v = wave_sum(v);
    if (lane == 0) ls[wave] = v;
    __syncthreads();
    if (tid == 0)
        out[0] = (ls[0] + ls[1] + ls[2] + ls[3]) * (1.0f / (2.0f * BATCH));
}

extern "C" void kernel_launch(void* const* d_in, const int* in_sizes, int n_in,
                              void* d_out, int out_size, void* d_ws, size_t ws_size,
                              hipStream_t stream) {
    const float* img = (const float*)d_in[0];   // [2B, D] fp32
    const float* mb  = (const float*)d_in[1];   // [M, D]  fp32
    float* out = (float*)d_out;
    float* ws  = (float*)d_ws;                  // needs (64*1024 + 1024 + 512)*4 B ≈ 268 KB

    hipLaunchKernelGGL(mb_sum_kernel,  dim3(NA_BLOCKS), dim3(NA_THREADS), 0, stream, mb, ws);
    hipLaunchKernelGGL(s_reduce_kernel, dim3(4),        dim3(256),        0, stream, ws);
    hipLaunchKernelGGL(img_kernel,     dim3(NC_BLOCKS), dim3(NC_THREADS), 0, stream, img, ws);
    hipLaunchKernelGGL(final_kernel,   dim3(1),         dim3(256),        0, stream, ws, out);
}